// Round 1
// baseline (587.910 us; speedup 1.0000x reference)
//
#include <hip/hip_runtime.h>
#include <hip/hip_bf16.h>

// GCN 2-layer: h1 = relu(Ahat @ (x@W1) + b1); out = Ahat @ (h1@W2) + b2
// Ahat = D^-1/2 (A + I) D^-1/2, pull-based aggregation over a CSR built per call.

#define WAVE 64

// ---- CSR build -------------------------------------------------------------

__global__ void k_deg(const int* __restrict__ ei, int E, int* __restrict__ deg) {
    int e = blockIdx.x * blockDim.x + threadIdx.x;
    if (e < E) atomicAdd(&deg[ei[E + e]], 1);  // row 1 of edge_index = dst
}

__global__ void k_scan_block(const int* __restrict__ in, int n,
                             int* __restrict__ out /* = offs+1 */,
                             int* __restrict__ bsum) {
    __shared__ int sm[256];
    int t = threadIdx.x;
    int g = blockIdx.x * 256 + t;
    int v = (g < n) ? in[g] : 0;
    sm[t] = v;
    __syncthreads();
    for (int off = 1; off < 256; off <<= 1) {
        int u = (t >= off) ? sm[t - off] : 0;
        __syncthreads();
        sm[t] += u;
        __syncthreads();
    }
    if (g < n) out[g] = sm[t];                  // local inclusive scan
    if (t == 255) bsum[blockIdx.x] = sm[255];   // block total
}

__global__ void k_scan_bsums(int* __restrict__ bsum, int nb) {
    __shared__ int sm[256];
    int t = threadIdx.x;
    int v = (t < nb) ? bsum[t] : 0;
    sm[t] = v;
    __syncthreads();
    for (int off = 1; off < 256; off <<= 1) {
        int u = (t >= off) ? sm[t - off] : 0;
        __syncthreads();
        sm[t] += u;
        __syncthreads();
    }
    if (t < nb) bsum[t] = sm[t];                // inclusive scan of block sums
}

__global__ void k_scan_add(int* __restrict__ offs, const int* __restrict__ bsum, int n) {
    int g = blockIdx.x * 256 + threadIdx.x;
    if (g == 0) offs[0] = 0;
    if (g < n) {
        int b = g >> 8;
        if (b > 0) offs[g + 1] += bsum[b - 1];
    }
}

__global__ void k_dinv(const int* __restrict__ deg, int n, float* __restrict__ dinv) {
    int i = blockIdx.x * blockDim.x + threadIdx.x;
    if (i < n) dinv[i] = 1.0f / sqrtf((float)(deg[i] + 1));  // +1 self-loop
}

__global__ void k_fill(const int* __restrict__ ei, int E,
                       const int* __restrict__ offs, int* __restrict__ cnt,
                       int* __restrict__ ssrc) {
    int e = blockIdx.x * blockDim.x + threadIdx.x;
    if (e < E) {
        int d = ei[E + e];
        int p = offs[d] + atomicAdd(&cnt[d], 1);
        ssrc[p] = ei[e];
    }
}

// ---- GEMM: H[n,64] = X[n,K] @ W[K,64] --------------------------------------
// Wave-per-row: lane c accumulates column c. W staged in LDS (K*64*4 bytes).

template <int K>
__global__ void k_gemm(const float* __restrict__ X, const float* __restrict__ W,
                       float* __restrict__ H, int n) {
    __shared__ float Wl[K * 64];
    for (int i = threadIdx.x; i < K * 64; i += blockDim.x) Wl[i] = W[i];
    __syncthreads();

    int lane = threadIdx.x & 63;
    int wavesPerBlock = blockDim.x >> 6;
    int waveId = blockIdx.x * wavesPerBlock + (threadIdx.x >> 6);
    int nwaves = gridDim.x * wavesPerBlock;

    for (int row = waveId; row < n; row += nwaves) {
        const float4* xr = (const float4*)(X + (size_t)row * K);
        float acc = 0.0f;
#pragma unroll 8
        for (int k4 = 0; k4 < K / 4; ++k4) {
            float4 xv = xr[k4];  // same addr across wave -> broadcast from L1
            acc += xv.x * Wl[(k4 * 4 + 0) * 64 + lane];
            acc += xv.y * Wl[(k4 * 4 + 1) * 64 + lane];
            acc += xv.z * Wl[(k4 * 4 + 2) * 64 + lane];
            acc += xv.w * Wl[(k4 * 4 + 3) * 64 + lane];
        }
        H[(size_t)row * 64 + lane] = acc;
    }
}

// ---- Aggregation: out[i] = dinv[i]*(sum_e dinv[s]*h[s] + dinv[i]*h[i]) + b --
// Wave per node, lane = channel (64 channels). Coalesced 256B gather per edge.

template <bool RELU>
__global__ void k_agg(const float* __restrict__ h, const int* __restrict__ offs,
                      const int* __restrict__ ssrc, const float* __restrict__ dinv,
                      const float* __restrict__ bias, float* __restrict__ out, int n) {
    int wavesPerBlock = blockDim.x >> 6;
    int node = blockIdx.x * wavesPerBlock + (threadIdx.x >> 6);
    if (node >= n) return;
    int lane = threadIdx.x & 63;

    int beg = offs[node];
    int end = offs[node + 1];
    float di = dinv[node];
    float acc = di * h[(size_t)node * 64 + lane];  // self-loop term

    int p = beg;
    for (; p + 3 < end; p += 4) {
        int s0 = ssrc[p + 0], s1 = ssrc[p + 1], s2 = ssrc[p + 2], s3 = ssrc[p + 3];
        float d0 = dinv[s0], d1 = dinv[s1], d2 = dinv[s2], d3 = dinv[s3];
        float v0 = h[(size_t)s0 * 64 + lane];
        float v1 = h[(size_t)s1 * 64 + lane];
        float v2 = h[(size_t)s2 * 64 + lane];
        float v3 = h[(size_t)s3 * 64 + lane];
        acc += d0 * v0 + d1 * v1 + d2 * v2 + d3 * v3;
    }
    for (; p < end; ++p) {
        int s = ssrc[p];
        acc += dinv[s] * h[(size_t)s * 64 + lane];
    }

    float r = di * acc + bias[lane];
    if (RELU) r = fmaxf(r, 0.0f);
    out[(size_t)node * 64 + lane] = r;
}

// ---- launch ----------------------------------------------------------------

extern "C" void kernel_launch(void* const* d_in, const int* in_sizes, int n_in,
                              void* d_out, int out_size, void* d_ws, size_t ws_size,
                              hipStream_t stream) {
    const float* x  = (const float*)d_in[0];
    const int*   ei = (const int*)d_in[1];
    const float* W1 = (const float*)d_in[2];
    const float* b1 = (const float*)d_in[3];
    const float* W2 = (const float*)d_in[4];
    const float* b2 = (const float*)d_in[5];

    const int n = in_sizes[0] / 256;   // 50000
    const int E = in_sizes[1] / 2;     // 1600000

    // workspace carve-up (256B aligned)
    char* ws = (char*)d_ws;
    auto carve = [&](size_t bytes) {
        void* p = (void*)ws;
        ws += (bytes + 255) & ~(size_t)255;
        return p;
    };
    int*   deg  = (int*)carve((size_t)n * 4);
    int*   offs = (int*)carve((size_t)(n + 1) * 4);
    int*   cnt  = (int*)carve((size_t)n * 4);
    int*   bsum = (int*)carve(256 * 4);
    int*   ssrc = (int*)carve((size_t)E * 4);
    float* dinv = (float*)carve((size_t)n * 4);
    float* hA   = (float*)carve((size_t)n * 64 * 4);
    float* hB   = (float*)carve((size_t)n * 64 * 4);

    hipMemsetAsync(deg, 0, (size_t)n * 4, stream);
    hipMemsetAsync(cnt, 0, (size_t)n * 4, stream);

    const int nbE = (E + 255) / 256;
    const int nbN = (n + 255) / 256;   // 196 (<=256 required by k_scan_bsums)

    k_deg<<<nbE, 256, 0, stream>>>(ei, E, deg);
    k_scan_block<<<nbN, 256, 0, stream>>>(deg, n, offs + 1, bsum);
    k_scan_bsums<<<1, 256, 0, stream>>>(bsum, nbN);
    k_scan_add<<<nbN, 256, 0, stream>>>(offs, bsum, n);
    k_dinv<<<nbN, 256, 0, stream>>>(deg, n, dinv);
    k_fill<<<nbE, 256, 0, stream>>>(ei, E, offs, cnt, ssrc);

    // layer 1: hA = x@W1 ; hB = relu(Ahat@hA + b1)
    k_gemm<256><<<512, 256, 0, stream>>>(x, W1, hA, n);
    k_agg<true><<<(n + 3) / 4, 256, 0, stream>>>(hA, offs, ssrc, dinv, b1, hB, n);

    // layer 2: hA = hB@W2 ; out = Ahat@hA + b2
    k_gemm<64><<<512, 256, 0, stream>>>(hB, W2, hA, n);
    k_agg<false><<<(n + 3) / 4, 256, 0, stream>>>(hA, offs, ssrc, dinv, b2,
                                                  (float*)d_out, n);
}

// Round 2
// 417.593 us; speedup vs baseline: 1.4079x; 1.4079x over previous
//
#include <hip/hip_runtime.h>
#include <hip/hip_bf16.h>

// GCN 2-layer: h1 = relu(Ahat @ (x@W1) + b1); out = Ahat @ (h1@W2) + b2
// Ahat = D^-1/2 (A + I) D^-1/2, pull-based aggregation over a CSR built per call.

// ---- CSR build -------------------------------------------------------------

__global__ void k_deg(const int* __restrict__ ei, int E, int* __restrict__ deg) {
    int e = blockIdx.x * blockDim.x + threadIdx.x;
    if (e < E) atomicAdd(&deg[ei[E + e]], 1);  // row 1 of edge_index = dst
}

__global__ void k_scan_block(const int* __restrict__ in, int n,
                             int* __restrict__ out /* = offs+1 */,
                             int* __restrict__ bsum) {
    __shared__ int sm[256];
    int t = threadIdx.x;
    int g = blockIdx.x * 256 + t;
    int v = (g < n) ? in[g] : 0;
    sm[t] = v;
    __syncthreads();
    for (int off = 1; off < 256; off <<= 1) {
        int u = (t >= off) ? sm[t - off] : 0;
        __syncthreads();
        sm[t] += u;
        __syncthreads();
    }
    if (g < n) out[g] = sm[t];                  // local inclusive scan
    if (t == 255) bsum[blockIdx.x] = sm[255];   // block total
}

__global__ void k_scan_bsums(int* __restrict__ bsum, int nb) {
    __shared__ int sm[256];
    int t = threadIdx.x;
    int v = (t < nb) ? bsum[t] : 0;
    sm[t] = v;
    __syncthreads();
    for (int off = 1; off < 256; off <<= 1) {
        int u = (t >= off) ? sm[t - off] : 0;
        __syncthreads();
        sm[t] += u;
        __syncthreads();
    }
    if (t < nb) bsum[t] = sm[t];                // inclusive scan of block sums
}

__global__ void k_scan_add(int* __restrict__ offs, const int* __restrict__ bsum, int n) {
    int g = blockIdx.x * 256 + threadIdx.x;
    if (g == 0) offs[0] = 0;
    if (g < n) {
        int b = g >> 8;
        if (b > 0) offs[g + 1] += bsum[b - 1];
    }
}

__global__ void k_dinv(const int* __restrict__ deg, int n, float* __restrict__ dinv) {
    int i = blockIdx.x * blockDim.x + threadIdx.x;
    if (i < n) dinv[i] = 1.0f / sqrtf((float)(deg[i] + 1));  // +1 self-loop
}

__global__ void k_fill(const int* __restrict__ ei, int E,
                       const int* __restrict__ offs, int* __restrict__ cnt,
                       int* __restrict__ ssrc) {
    int e = blockIdx.x * blockDim.x + threadIdx.x;
    if (e < E) {
        int d = ei[E + e];
        int p = offs[d] + atomicAdd(&cnt[d], 1);
        ssrc[p] = ei[e];
    }
}

// ---- GEMM: H[n,64] = X[n,K] @ W[K,64] --------------------------------------
// Register-tiled: block(256) computes 64 rows x 64 cols; thread = 4x4 tile.
// x staged coalesced to LDS (stride-36 pad, conflict-free b128 broadcast reads);
// W staged 32x64 per k-tile. 64 FMA per 8 ds_read_b128 -> FMA-limited.

#define FMA4(A, s, wv)                                                         \
    (A).x += (s) * (wv).x; (A).y += (s) * (wv).y;                              \
    (A).z += (s) * (wv).z; (A).w += (s) * (wv).w;

template <int K>
__global__ __launch_bounds__(256) void k_gemm(const float* __restrict__ X,
                                              const float* __restrict__ W,
                                              float* __restrict__ H, int n) {
    __shared__ float xl[64][36];  // 64 rows x 32 k, +4 pad (16B-aligned rows)
    __shared__ float wl[32][64];

    const int t = threadIdx.x;
    const int tc = t & 15;   // col group: cols tc*4 .. tc*4+3
    const int tr = t >> 4;   // row group: rows tr*4 .. tr*4+3
    const int row0 = blockIdx.x * 64;

    float4 acc[4];
    acc[0] = acc[1] = acc[2] = acc[3] = make_float4(0.f, 0.f, 0.f, 0.f);

    for (int k0 = 0; k0 < K; k0 += 32) {
        // stage x tile: 64 rows x 32 floats = 512 float4, 2 per thread, coalesced
#pragma unroll
        for (int i = 0; i < 2; ++i) {
            int idx = i * 256 + t;
            int r = idx >> 3, f4 = idx & 7;
            int gr = row0 + r;
            float4 v = make_float4(0.f, 0.f, 0.f, 0.f);
            if (gr < n) v = *(const float4*)(X + (size_t)gr * K + k0 + f4 * 4);
            *(float4*)&xl[r][f4 * 4] = v;
        }
        // stage W tile: 32 x 64 = 512 float4, 2 per thread, coalesced
#pragma unroll
        for (int i = 0; i < 2; ++i) {
            int idx = i * 256 + t;
            int kr = idx >> 4, f4 = idx & 15;
            *(float4*)&wl[kr][f4 * 4] =
                *(const float4*)(W + (size_t)(k0 + kr) * 64 + f4 * 4);
        }
        __syncthreads();

#pragma unroll
        for (int kk = 0; kk < 32; kk += 4) {
            float4 xv0 = *(float4*)&xl[tr * 4 + 0][kk];
            float4 xv1 = *(float4*)&xl[tr * 4 + 1][kk];
            float4 xv2 = *(float4*)&xl[tr * 4 + 2][kk];
            float4 xv3 = *(float4*)&xl[tr * 4 + 3][kk];
            float4 wv0 = *(float4*)&wl[kk + 0][tc * 4];
            float4 wv1 = *(float4*)&wl[kk + 1][tc * 4];
            float4 wv2 = *(float4*)&wl[kk + 2][tc * 4];
            float4 wv3 = *(float4*)&wl[kk + 3][tc * 4];

            FMA4(acc[0], xv0.x, wv0); FMA4(acc[0], xv0.y, wv1);
            FMA4(acc[0], xv0.z, wv2); FMA4(acc[0], xv0.w, wv3);
            FMA4(acc[1], xv1.x, wv0); FMA4(acc[1], xv1.y, wv1);
            FMA4(acc[1], xv1.z, wv2); FMA4(acc[1], xv1.w, wv3);
            FMA4(acc[2], xv2.x, wv0); FMA4(acc[2], xv2.y, wv1);
            FMA4(acc[2], xv2.z, wv2); FMA4(acc[2], xv2.w, wv3);
            FMA4(acc[3], xv3.x, wv0); FMA4(acc[3], xv3.y, wv1);
            FMA4(acc[3], xv3.z, wv2); FMA4(acc[3], xv3.w, wv3);
        }
        __syncthreads();
    }

#pragma unroll
    for (int ri = 0; ri < 4; ++ri) {
        int gr = row0 + tr * 4 + ri;
        if (gr < n) *(float4*)(H + (size_t)gr * 64 + tc * 4) = acc[ri];
    }
}

// ---- Aggregation: out[i] = dinv[i]*(sum_e dinv[s]*h[s] + dinv[i]*h[i]) + b --
// Wave per node, lane = channel (64 channels). Coalesced 256B gather per edge.

template <bool RELU>
__global__ void k_agg(const float* __restrict__ h, const int* __restrict__ offs,
                      const int* __restrict__ ssrc, const float* __restrict__ dinv,
                      const float* __restrict__ bias, float* __restrict__ out, int n) {
    int wavesPerBlock = blockDim.x >> 6;
    int node = blockIdx.x * wavesPerBlock + (threadIdx.x >> 6);
    if (node >= n) return;
    int lane = threadIdx.x & 63;

    int beg = offs[node];
    int end = offs[node + 1];
    float di = dinv[node];
    float acc = di * h[(size_t)node * 64 + lane];  // self-loop term

    int p = beg;
    for (; p + 3 < end; p += 4) {
        int s0 = ssrc[p + 0], s1 = ssrc[p + 1], s2 = ssrc[p + 2], s3 = ssrc[p + 3];
        float d0 = dinv[s0], d1 = dinv[s1], d2 = dinv[s2], d3 = dinv[s3];
        float v0 = h[(size_t)s0 * 64 + lane];
        float v1 = h[(size_t)s1 * 64 + lane];
        float v2 = h[(size_t)s2 * 64 + lane];
        float v3 = h[(size_t)s3 * 64 + lane];
        acc += d0 * v0 + d1 * v1 + d2 * v2 + d3 * v3;
    }
    for (; p < end; ++p) {
        int s = ssrc[p];
        acc += dinv[s] * h[(size_t)s * 64 + lane];
    }

    float r = di * acc + bias[lane];
    if (RELU) r = fmaxf(r, 0.0f);
    out[(size_t)node * 64 + lane] = r;
}

// ---- launch ----------------------------------------------------------------

extern "C" void kernel_launch(void* const* d_in, const int* in_sizes, int n_in,
                              void* d_out, int out_size, void* d_ws, size_t ws_size,
                              hipStream_t stream) {
    const float* x  = (const float*)d_in[0];
    const int*   ei = (const int*)d_in[1];
    const float* W1 = (const float*)d_in[2];
    const float* b1 = (const float*)d_in[3];
    const float* W2 = (const float*)d_in[4];
    const float* b2 = (const float*)d_in[5];

    const int n = in_sizes[0] / 256;   // 50000
    const int E = in_sizes[1] / 2;     // 1600000

    // workspace carve-up (256B aligned)
    char* ws = (char*)d_ws;
    auto carve = [&](size_t bytes) {
        void* p = (void*)ws;
        ws += (bytes + 255) & ~(size_t)255;
        return p;
    };
    int*   deg  = (int*)carve((size_t)n * 4);
    int*   offs = (int*)carve((size_t)(n + 1) * 4);
    int*   cnt  = (int*)carve((size_t)n * 4);
    int*   bsum = (int*)carve(256 * 4);
    int*   ssrc = (int*)carve((size_t)E * 4);
    float* dinv = (float*)carve((size_t)n * 4);
    float* hA   = (float*)carve((size_t)n * 64 * 4);
    float* hB   = (float*)carve((size_t)n * 64 * 4);

    hipMemsetAsync(deg, 0, (size_t)n * 4, stream);
    hipMemsetAsync(cnt, 0, (size_t)n * 4, stream);

    const int nbE = (E + 255) / 256;
    const int nbN = (n + 255) / 256;   // 196 (<=256 required by k_scan_bsums)

    k_deg<<<nbE, 256, 0, stream>>>(ei, E, deg);
    k_scan_block<<<nbN, 256, 0, stream>>>(deg, n, offs + 1, bsum);
    k_scan_bsums<<<1, 256, 0, stream>>>(bsum, nbN);
    k_scan_add<<<nbN, 256, 0, stream>>>(offs, bsum, n);
    k_dinv<<<nbN, 256, 0, stream>>>(deg, n, dinv);
    k_fill<<<nbE, 256, 0, stream>>>(ei, E, offs, cnt, ssrc);

    const int nbG = (n + 63) / 64;  // 782

    // layer 1: hA = x@W1 ; hB = relu(Ahat@hA + b1)
    k_gemm<256><<<nbG, 256, 0, stream>>>(x, W1, hA, n);
    k_agg<true><<<(n + 3) / 4, 256, 0, stream>>>(hA, offs, ssrc, dinv, b1, hB, n);

    // layer 2: hA = hB@W2 ; out = Ahat@hA + b2
    k_gemm<64><<<nbG, 256, 0, stream>>>(hB, W2, hA, n);
    k_agg<false><<<(n + 3) / 4, 256, 0, stream>>>(hA, offs, ssrc, dinv, b2,
                                                  (float*)d_out, n);
}